// Round 15
// baseline (381.147 us; speedup 1.0000x reference)
//
#include <hip/hip_runtime.h>

typedef unsigned short ushort_t;
typedef __attribute__((ext_vector_type(8))) __bf16 bf16x8;
typedef __attribute__((ext_vector_type(4))) float f32x4;

constexpr int B_ = 8, N_ = 1025, C_ = 1024, H_ = 16, HD = 64;
constexpr int M_QKV = B_ * N_;          // 8200
constexpr int M_PROJ = 2 * B_ * N_;     // 16400
constexpr int K_ = 1024;
constexpr int NT = 1032;                // vT row stride (16B-aligned)
constexpr size_t S1 = (size_t)B_ * H_ * N_ * HD;    // 8,396,800
constexpr size_t VT_SZ = (size_t)B_ * H_ * HD * NT; // 8,454,144

__device__ __forceinline__ ushort_t f2bf(float f) {
    union { float f; unsigned u; } a; a.f = f;
    unsigned r = a.u + 0x7FFFu + ((a.u >> 16) & 1u);
    return (ushort_t)(r >> 16);
}
__device__ __forceinline__ unsigned pk2(float x, float y) {
    unsigned a = __float_as_uint(x) + 0x8000u;
    unsigned b = __float_as_uint(y) + 0x8000u;
    return (a >> 16) | (b & 0xffff0000u);
}
__device__ __forceinline__ uint4 pack8(float4 x, float4 y) {
    return make_uint4(pk2(x.x, x.y), pk2(x.z, x.w), pk2(y.x, y.y), pk2(y.z, y.w));
}

union U4 { uint4 v; ushort_t s[8]; };

__device__ __forceinline__ void gload16(const ushort_t* g, ushort_t* l) {
    __builtin_amdgcn_global_load_lds(
        (const __attribute__((address_space(1))) void*)g,
        (__attribute__((address_space(3))) void*)l, 16, 0, 0);
}

// ---------------------------------------------------------------------------
__global__ __launch_bounds__(256)
void conv_bf16(const float* __restrict__ src, ushort_t* __restrict__ dst, int n8) {
    const int i = blockIdx.x * 256 + threadIdx.x;
    if (i < n8) {
        const float4* s = (const float4*)src + 2 * (size_t)i;
        ((uint4*)dst)[i] = pack8(s[0], s[1]);
    }
}

// ---------------------------------------------------------------------------
// GEMM 1: QKV = Xbf * Wbf^T, 128x128 tile, BK=64 (r15): halves the per-block
// barrier-drain count (64 -> 32) vs BK=32 — r9/r11 showed pipelining ACROSS
// barriers is null on this structure, so attack the barrier COUNT instead.
// [128][64]-ushort rows are 128B -> G4 32-way-conflict trap; fixed with the
// attn kernel's proven pre-swizzled-source XOR (scol ^ (srow&7), fragment
// reads ^ (l16&7)<<3). Two-barrier loop + XCD-aware 1-D grid (r10).
//   q written PRE-SCALED by 0.125 (exact in bf16); k,v plain; vT transposed v.
// ---------------------------------------------------------------------------
__global__ __launch_bounds__(256)
void gemm_qkv(const ushort_t* __restrict__ A, const ushort_t* __restrict__ Bm,
              ushort_t* __restrict__ q, ushort_t* __restrict__ k,
              ushort_t* __restrict__ v, ushort_t* __restrict__ vT) {
    // XCD decode: 1728 blocks = 8 xcd x (24 n x 9 m_local)
    const int lin = blockIdx.x;
    const int xcd = lin & 7;
    const int j = lin >> 3;            // 0..215
    const int m_local = j % 9;         // m fastest within XCD
    const int n_idx = j / 9;           // 0..23
    const int m_idx = xcd * 9 + m_local;  // 0..71
    if (m_idx >= 65) return;
    const int m0 = m_idx * 128, n0 = n_idx * 128;

    __shared__ ushort_t As[128 * 64];   // 16 KB, swizzled rows
    __shared__ ushort_t Bs[128 * 64];   // 16 KB, swizzled rows
    const int tid = threadIdx.x;
    const int wave = tid >> 6, lane = tid & 63;
    const int quad = lane >> 4, l16 = lane & 15;
    const int wm = (wave & 1) * 64, wn = (wave >> 1) * 64;
    const int swz = (l16 & 7) << 3;     // fragment-read XOR (ushort units)

    // staging: thread covers 4 rows (srow + 32*i), one swizzled 16B chunk each
    const int srow = tid >> 3;                        // 0..31
    const int scc  = 8 * ((tid & 7) ^ (srow & 7));    // pre-swizzled source col
    const ushort_t* gA[4];
    const ushort_t* gB[4];
#pragma unroll
    for (int i = 0; i < 4; i++) {
        const int ar = min(m0 + srow + 32 * i, M_QKV - 1);
        gA[i] = A + (size_t)ar * K_ + scc;
        gB[i] = Bm + (size_t)(n0 + srow + 32 * i) * K_ + scc;
    }

    f32x4 acc[4][4] = {};

    for (int k0 = 0; k0 < K_; k0 += 64) {
        __syncthreads();
#pragma unroll
        for (int i = 0; i < 4; i++) {
            gload16(gA[i] + k0, As + tid * 8 + i * 2048);
            gload16(gB[i] + k0, Bs + tid * 8 + i * 2048);
        }
        __syncthreads();
#pragma unroll
        for (int ks = 0; ks < 2; ks++) {
            bf16x8 af[4], bfr[4];
#pragma unroll
            for (int i = 0; i < 4; i++) {
                af[i]  = *(const bf16x8*)(As + (wm + i * 16 + l16) * 64 + ((ks * 32 + quad * 8) ^ swz));
                bfr[i] = *(const bf16x8*)(Bs + (wn + i * 16 + l16) * 64 + ((ks * 32 + quad * 8) ^ swz));
            }
#pragma unroll
            for (int im = 0; im < 4; im++)
#pragma unroll
                for (int in = 0; in < 4; in++)
                    acc[im][in] = __builtin_amdgcn_mfma_f32_16x16x32_bf16(af[im], bfr[in], acc[im][in], 0, 0, 0);
        }
    }

#pragma unroll
    for (int im = 0; im < 4; im++) {
#pragma unroll
        for (int in = 0; in < 4; in++) {
            const int gcol = n0 + wn + in * 16 + l16;     // 0..3071
            const int which = gcol >> 10;                 // 0/1/2
            const int c = gcol & 1023;
            const int h = c >> 6, d = c & 63;
            ushort_t* dst = which == 0 ? q : (which == 1 ? k : v);
            const float sc = (which == 0) ? 0.125f : 1.0f;  // pre-scale q
#pragma unroll
            for (int r = 0; r < 4; r++) {
                const int grow = m0 + wm + im * 16 + quad * 4 + r;
                if (grow < M_QKV) {
                    const int b = grow / N_;
                    const int nn = grow - b * N_;
                    const ushort_t val = f2bf(acc[im][in][r] * sc);
                    const size_t bh = (size_t)(b * H_ + h);
                    dst[(bh * N_ + nn) * HD + d] = val;
                    if (which == 2)
                        vT[(bh * HD + d) * NT + nn] = val;
                }
            }
        }
    }
}

// ---------------------------------------------------------------------------
// Attention (r8/r10/r14 best: ~136 us). Swapped QK^T (packed ds_write_b64
// P-stores, lane-local row-sums), XCD-swizzled grid, dbuf global_load_lds,
// __expf (libm exp2f regressed +33us, r5), NO Vt register hoist (r7 spill),
// Td STAYS LDS-staged (r13: de-staging cost 5x — scratch + L1 thrash).
// ---------------------------------------------------------------------------
__global__ __launch_bounds__(512, 4)
void attn_kernel(const ushort_t* __restrict__ q, const ushort_t* __restrict__ k,
                 const ushort_t* __restrict__ v, const ushort_t* __restrict__ vT,
                 ushort_t* __restrict__ xvv, ushort_t* __restrict__ xori) {
    __shared__ ushort_t Kd[2][64 * 64];   // k tile [key][dim], swizzled
    __shared__ ushort_t Vd[2][64 * 64];   // v tile [key][dim], swizzled
    __shared__ ushort_t Td[2][64 * 64];   // v^T tile [dim][key], swizzled
    __shared__ ushort_t Ps[8 * 16 * 64];  // [wave][qrow][key], chunk-swizzled

    const int tid = threadIdx.x;
    const int wave = tid >> 6, lane = tid & 63;
    const int quad = lane >> 4, l16 = lane & 15;

    // XCD-aware decode: lin = (bh&7) + 8*((bh>>3)*9 + qt)  [bijective]
    const int lin = blockIdx.x;
    const int r8 = lin & 7;
    const int j = lin >> 3;            // 0..143
    const int g = j / 9;               // 0..15
    const int qt = j - g * 9;          // 0..8
    const int bh = g * 8 + r8;         // 0..127
    const int b = bh >> 4, h = bh & 15;

    const size_t base  = (size_t)bh * N_ * HD;
    const size_t baseT = (size_t)bh * HD * NT;
    const int qstart = min(qt * 128, N_ - 128);
    const int qr0 = qstart + wave * 16;

    // swizzle constants
    const int swz  = (l16 & 7) << 3;      // tile fragment-read XOR (ushort units)
    const int a7   = l16 & 7;             // Ps chunk XOR
    const int prow = (wave * 16 + l16) * 64;  // Ps row base (ushort units)
    const int kq4  = quad * 4;            // per-lane key sub-offset

    // staging geometry: 512 threads cover one 16B chunk per array each
    const int srow = tid >> 3;                       // 0..63
    const int scol = 8 * ((tid & 7) ^ (srow & 7));   // pre-swizzled source col (us)
    const int ld = tid * 8;                          // LDS dest offset (us)

    // Q fragments (always in-bounds); B-operand role (cols = q-rows)
    bf16x8 qq[2], qv[2];
    {
        const int qrow = qr0 + l16;
#pragma unroll
        for (int kk = 0; kk < 2; kk++) {
            U4 uq, uv;
            uq.v = *(const uint4*)(q + base + (size_t)qrow * HD + kk * 32 + quad * 8);
            uv.v = *(const uint4*)(v + base + (size_t)qrow * HD + kk * 32 + quad * 8);
            qq[kk] = *(const bf16x8*)uq.s;
            qv[kk] = *(const bf16x8*)uv.s;
        }
    }

    float l0 = 0.f, l1 = 0.f;          // row-sum for qrow l16 (this quad's keys)
    f32x4 o0[4] = {}, o1[4] = {};

    const int nkt = (N_ + 63) / 64;   // 17

    // ---- prologue: stage tile 0 into buffer 0 (keys 0..63 all valid) ----
    gload16(k + base + (size_t)srow * HD + scol,   &Kd[0][ld]);
    gload16(v + base + (size_t)srow * HD + scol,   &Vd[0][ld]);
    gload16(vT + baseT + (size_t)srow * NT + scol, &Td[0][ld]);

    for (int kt = 0; kt < nkt; kt++) {
        const int key0 = kt * 64;
        const bool tail = (key0 + 64 > N_);
        const int cur = kt & 1;

        __syncthreads();   // implicit vmcnt(0): stage(kt) landed; buf[cur^1] free

        // ---- issue next-tile stage into the other buffer (async DMA) ----
        if (kt + 1 < nkt) {
            const int kn = key0 + 64;
            const int nb = cur ^ 1;
            const int kk0 = min(kn + srow, N_ - 1);       // clamp: masked -> P=0
            gload16(k + base + (size_t)kk0 * HD + scol, &Kd[nb][ld]);
            gload16(v + base + (size_t)kk0 * HD + scol, &Vd[nb][ld]);
            gload16(vT + baseT + (size_t)srow * NT + kn + scol, &Td[nb][ld]);
        }

        const ushort_t* Kc = Kd[cur];
        const ushort_t* Vc = Vd[cur];
        const ushort_t* Tc = Td[cur];

        // ---- path 0: S^T = K·(q/8)^T  (swapped operands) ----
        f32x4 s[4];
        __builtin_amdgcn_s_setprio(1);
#pragma unroll
        for (int t = 0; t < 4; t++) {
            const int row = (t * 16 + l16) * 64;
            bf16x8 b0 = *(const bf16x8*)(Kc + row + ((quad * 8) ^ swz));
            bf16x8 b1 = *(const bf16x8*)(Kc + row + ((32 + quad * 8) ^ swz));
            f32x4 a = {};
            a = __builtin_amdgcn_mfma_f32_16x16x32_bf16(b0, qq[0], a, 0, 0, 0);
            a = __builtin_amdgcn_mfma_f32_16x16x32_bf16(b1, qq[1], a, 0, 0, 0);
            s[t] = a;   // s[t][r] = S[key0+t*16+quad*4+r][qrow=l16]
        }
        __builtin_amdgcn_s_setprio(0);

        if (tail) {
#pragma unroll
            for (int t = 0; t < 4; t++)
#pragma unroll
                for (int r = 0; r < 4; r++)
                    if (key0 + t * 16 + kq4 + r >= N_) s[t][r] = -1e30f;
        }
#pragma unroll
        for (int t = 0; t < 4; t++) {
            const float p0 = __expf(s[t][0]);
            const float p1 = __expf(s[t][1]);
            const float p2 = __expf(s[t][2]);
            const float p3 = __expf(s[t][3]);
            l0 += (p0 + p1) + (p2 + p3);
            *(uint2*)(&Ps[prow + (((t * 4 + quad) >> 1) ^ a7) * 8 + (quad & 1) * 4]) =
                make_uint2(pk2(p0, p1), pk2(p2, p3));
        }
        {
            bf16x8 pa0 = *(const bf16x8*)(&Ps[prow + ((quad    ) ^ a7) * 8]);
            bf16x8 pa1 = *(const bf16x8*)(&Ps[prow + ((quad + 4) ^ a7) * 8]);
            __builtin_amdgcn_s_setprio(1);
#pragma unroll
            for (int t = 0; t < 4; t++) {
                const int row = (t * 16 + l16) * 64;
                bf16x8 bv0 = *(const bf16x8*)(Tc + row + ((quad * 8) ^ swz));
                bf16x8 bv1 = *(const bf16x8*)(Tc + row + ((32 + quad * 8) ^ swz));
                o0[t] = __builtin_amdgcn_mfma_f32_16x16x32_bf16(pa0, bv0, o0[t], 0, 0, 0);
                o0[t] = __builtin_amdgcn_mfma_f32_16x16x32_bf16(pa1, bv1, o0[t], 0, 0, 0);
            }
            __builtin_amdgcn_s_setprio(0);
        }

        // ---- path 1: S^T = V·v^T / 8  (swapped operands) ----
        __builtin_amdgcn_s_setprio(1);
#pragma unroll
        for (int t = 0; t < 4; t++) {
            const int row = (t * 16 + l16) * 64;
            bf16x8 b0 = *(const bf16x8*)(Vc + row + ((quad * 8) ^ swz));
            bf16x8 b1 = *(const bf16x8*)(Vc + row + ((32 + quad * 8) ^ swz));
            f32x4 a = {};
            a = __builtin_amdgcn_mfma_f32_16x16x32_bf16(b0, qv[0], a, 0, 0, 0);
            a = __builtin_amdgcn_mfma_f32_16x16x32_bf16(b1, qv[1], a, 0, 0, 0);
            s[t] = a;
        }
        __builtin_amdgcn_s_setprio(0);
        if (tail) {
#pragma unroll
            for (int t = 0; t < 4; t++)
#pragma unroll
                for (int r = 0; r < 4; r++)
                    if (key0 + t * 16 + kq4 + r >= N_) s[t][r] = -1e30f;
        }
#pragma unroll
        for (int t = 0; t < 4; t++) {
            const float p0 = __expf(s[t][0] * 0.125f);
            const float p1 = __expf(s[t][1] * 0.125f);
            const float p2 = __expf(s[t][2] * 0.125f);
            const float p3 = __expf(s[t][3] * 0.125f);
            l1 += (p0 + p1) + (p2 + p3);
            *(uint2*)(&Ps[prow + (((t * 4 + quad) >> 1) ^ a7) * 8 + (quad & 1) * 4]) =
                make_uint2(pk2(p0, p1), pk2(p2, p3));
        }
        {
            bf16x8 pa0 = *(const bf16x8*)(&Ps[prow + ((quad    ) ^ a7) * 8]);
            bf16x8 pa1 = *(const bf16x8*)(&Ps[prow + ((quad + 4) ^ a7) * 8]);
            __builtin_amdgcn_s_setprio(1);
#pragma unroll
            for (int t = 0; t < 4; t++) {
                const int row = (t * 16 + l16) * 64;
                bf16x8 bv0 = *(const bf16x8*)(Tc + row + ((quad * 8) ^ swz));
                bf16x8 bv1 = *(const bf16x8*)(Tc + row + ((32 + quad * 8) ^ swz));
                o1[t] = __builtin_amdgcn_mfma_f32_16x16x32_bf16(pa0, bv0, o1[t], 0, 0, 0);
                o1[t] = __builtin_amdgcn_mfma_f32_16x16x32_bf16(pa1, bv1, o1[t], 0, 0, 0);
            }
            __builtin_amdgcn_s_setprio(0);
        }
    }

    // ---- epilogue ----
    l0 += __shfl_xor(l0, 16);
    l0 += __shfl_xor(l0, 32);
    l1 += __shfl_xor(l1, 16);
    l1 += __shfl_xor(l1, 32);
#pragma unroll
    for (int r = 0; r < 4; r++) {
        const float inv0 = 1.0f / __shfl(l0, kq4 + r);   // L(qrow=quad*4+r)
        const float inv1 = 1.0f / __shfl(l1, kq4 + r);
        const int row = qr0 + kq4 + r;
        const size_t rb = (size_t)(b * N_ + row) * C_ + h * HD;
#pragma unroll
        for (int t = 0; t < 4; t++) {
            const int d = t * 16 + l16;
            xori[rb + d] = f2bf(o0[t][r] * inv0);
            xvv[rb + d]  = f2bf(o1[t][r] * inv1);
        }
    }
}

// ---------------------------------------------------------------------------
// GEMM 2: OUT(f32) = Xcat(bf16) * Wbf^T + bias. BK=64 swizzled (r15) +
// two-barrier K-loop + XCD-aware 1-D grid (r10).
// ---------------------------------------------------------------------------
__global__ __launch_bounds__(256)
void gemm_proj(const ushort_t* __restrict__ A, const ushort_t* __restrict__ Bm,
               const float* __restrict__ bias, float* __restrict__ out) {
    const int lin = blockIdx.x;
    const int xcd = lin & 7;
    const int j = lin >> 3;             // 0..135
    const int m_local = j % 17;         // m fastest within XCD
    const int n_idx = j / 17;           // 0..7
    const int m_idx = xcd * 17 + m_local;  // 0..135
    if (m_idx >= 129) return;
    const int m0 = m_idx * 128, n0 = n_idx * 128;

    __shared__ ushort_t As[128 * 64];
    __shared__ ushort_t Bs[128 * 64];
    const int tid = threadIdx.x;
    const int wave = tid >> 6, lane = tid & 63;
    const int quad = lane >> 4, l16 = lane & 15;
    const int wm = (wave & 1) * 64, wn = (wave >> 1) * 64;
    const int swz = (l16 & 7) << 3;

    const int srow = tid >> 3;                        // 0..31
    const int scc  = 8 * ((tid & 7) ^ (srow & 7));
    const ushort_t* gA[4];
    const ushort_t* gB[4];
#pragma unroll
    for (int i = 0; i < 4; i++) {
        const int ar = min(m0 + srow + 32 * i, M_PROJ - 1);
        gA[i] = A + (size_t)ar * K_ + scc;
        gB[i] = Bm + (size_t)(n0 + srow + 32 * i) * K_ + scc;
    }

    f32x4 acc[4][4] = {};

    for (int k0 = 0; k0 < K_; k0 += 64) {
        __syncthreads();
#pragma unroll
        for (int i = 0; i < 4; i++) {
            gload16(gA[i] + k0, As + tid * 8 + i * 2048);
            gload16(gB[i] + k0, Bs + tid * 8 + i * 2048);
        }
        __syncthreads();
#pragma unroll
        for (int ks = 0; ks < 2; ks++) {
            bf16x8 af[4], bfr[4];
#pragma unroll
            for (int i = 0; i < 4; i++) {
                af[i]  = *(const bf16x8*)(As + (wm + i * 16 + l16) * 64 + ((ks * 32 + quad * 8) ^ swz));
                bfr[i] = *(const bf16x8*)(Bs + (wn + i * 16 + l16) * 64 + ((ks * 32 + quad * 8) ^ swz));
            }
#pragma unroll
            for (int im = 0; im < 4; im++)
#pragma unroll
                for (int in = 0; in < 4; in++)
                    acc[im][in] = __builtin_amdgcn_mfma_f32_16x16x32_bf16(af[im], bfr[in], acc[im][in], 0, 0, 0);
        }
    }

#pragma unroll
    for (int im = 0; im < 4; im++) {
#pragma unroll
        for (int in = 0; in < 4; in++) {
            const int gcol = n0 + wn + in * 16 + l16;
            const float bb = bias[gcol];
#pragma unroll
            for (int r = 0; r < 4; r++) {
                const int grow = m0 + wm + im * 16 + quad * 4 + r;
                if (grow < M_PROJ)
                    out[(size_t)grow * C_ + gcol] = acc[im][in][r] + bb;
            }
        }
    }
}

// ---------------------------------------------------------------------------
// Memory map:
//   d_ws  [0,S1)      : x_bf (phase 1), then xvv   [aliased]
//   d_ws  [S1,2S1)    : xori
//   d_ws  [2S1,3S1)   : v (phases 1-3), then wproj_bf [aliased, conv after attn]
//   d_out [0,S1)      : q (pre-scaled 1/8)   [dead before proj writes]
//   d_out [S1,2S1)    : k
//   d_out [2S1,2S1+VT): vT
//   d_out [2S1+VT,..) : wqkv_bf
// ---------------------------------------------------------------------------
extern "C" void kernel_launch(void* const* d_in, const int* in_sizes, int n_in,
                              void* d_out, int out_size, void* d_ws, size_t ws_size,
                              hipStream_t stream) {
    const float* x      = (const float*)d_in[0];
    const float* w_qkv  = (const float*)d_in[1];
    const float* w_proj = (const float*)d_in[2];
    const float* b_proj = (const float*)d_in[3];
    float* out = (float*)d_out;

    ushort_t* ws = (ushort_t*)d_ws;
    ushort_t* x_bf     = ws;
    ushort_t* xvv      = ws;
    ushort_t* xori     = ws + S1;
    ushort_t* v        = ws + 2 * S1;
    ushort_t* wproj_bf = ws + 2 * S1;

    ushort_t* q        = (ushort_t*)d_out;
    ushort_t* k        = (ushort_t*)d_out + S1;
    ushort_t* vT       = (ushort_t*)d_out + 2 * S1;
    ushort_t* wqkv_bf  = (ushort_t*)d_out + 2 * S1 + VT_SZ;

    {
        const int n8x = (int)(S1 / 8);
        conv_bf16<<<(n8x + 255) / 256, 256, 0, stream>>>(x, x_bf, n8x);
        const int n8w = 3 * C_ * C_ / 8;
        conv_bf16<<<(n8w + 255) / 256, 256, 0, stream>>>(w_qkv, wqkv_bf, n8w);
    }
    {
        gemm_qkv<<<dim3(8 * 24 * 9), 256, 0, stream>>>(x_bf, wqkv_bf, q, k, v, vT);
    }
    {
        attn_kernel<<<dim3(9 * B_ * H_), 512, 0, stream>>>(q, k, v, vT, xvv, xori);
    }
    {
        const int n8p = C_ * C_ / 8;
        conv_bf16<<<(n8p + 255) / 256, 256, 0, stream>>>(w_proj, wproj_bf, n8p);
    }
    {
        gemm_proj<<<dim3(8 * 8 * 17), 256, 0, stream>>>(xvv, wproj_bf, b_proj, out);
    }
}

// Round 16
// 376.288 us; speedup vs baseline: 1.0129x; 1.0129x over previous
//
#include <hip/hip_runtime.h>

typedef unsigned short ushort_t;
typedef __attribute__((ext_vector_type(8))) __bf16 bf16x8;
typedef __attribute__((ext_vector_type(4))) float f32x4;

constexpr int B_ = 8, N_ = 1025, C_ = 1024, H_ = 16, HD = 64;
constexpr int M_QKV = B_ * N_;          // 8200
constexpr int M_PROJ = 2 * B_ * N_;     // 16400
constexpr int K_ = 1024;
constexpr int NT = 1032;                // vT row stride (16B-aligned)
constexpr size_t S1 = (size_t)B_ * H_ * N_ * HD;    // 8,396,800
constexpr size_t VT_SZ = (size_t)B_ * H_ * HD * NT; // 8,454,144

__device__ __forceinline__ ushort_t f2bf(float f) {
    union { float f; unsigned u; } a; a.f = f;
    unsigned r = a.u + 0x7FFFu + ((a.u >> 16) & 1u);
    return (ushort_t)(r >> 16);
}
__device__ __forceinline__ unsigned pk2(float x, float y) {
    unsigned a = __float_as_uint(x) + 0x8000u;
    unsigned b = __float_as_uint(y) + 0x8000u;
    return (a >> 16) | (b & 0xffff0000u);
}
__device__ __forceinline__ uint4 pack8(float4 x, float4 y) {
    return make_uint4(pk2(x.x, x.y), pk2(x.z, x.w), pk2(y.x, y.y), pk2(y.z, y.w));
}

union U4 { uint4 v; ushort_t s[8]; };

__device__ __forceinline__ void gload16(const ushort_t* g, ushort_t* l) {
    __builtin_amdgcn_global_load_lds(
        (const __attribute__((address_space(1))) void*)g,
        (__attribute__((address_space(3))) void*)l, 16, 0, 0);
}

// ---------------------------------------------------------------------------
__global__ __launch_bounds__(256)
void conv_bf16(const float* __restrict__ src, ushort_t* __restrict__ dst, int n8) {
    const int i = blockIdx.x * 256 + threadIdx.x;
    if (i < n8) {
        const float4* s = (const float4*)src + 2 * (size_t)i;
        ((uint4*)dst)[i] = pack8(s[0], s[1]);
    }
}

// Merged x + w_qkv conversion (one launch instead of two; branch is
// per-block-uniform except at the boundary block).
__global__ __launch_bounds__(256)
void conv_bf16_2(const float* __restrict__ s1, ushort_t* __restrict__ d1, int n1,
                 const float* __restrict__ s2, ushort_t* __restrict__ d2, int n2) {
    const int i = blockIdx.x * 256 + threadIdx.x;
    if (i < n1) {
        const float4* s = (const float4*)s1 + 2 * (size_t)i;
        ((uint4*)d1)[i] = pack8(s[0], s[1]);
    } else if (i - n1 < n2) {
        const int j = i - n1;
        const float4* s = (const float4*)s2 + 2 * (size_t)j;
        ((uint4*)d2)[j] = pack8(s[0], s[1]);
    }
}

// ---------------------------------------------------------------------------
// GEMM 1: QKV = Xbf * Wbf^T, 128x128x32 tiles. Two-barrier m97 K-loop —
// r9 dbuf / r11 counted-vmcnt / r15 BK=64 all measured null on this
// structure; at these shapes it sits AT the m97-structure ceiling (m102:
// ~320-460 TF) — the next step is the 256^2 8-phase template, not edits here.
// XCD-aware 1-D grid (r10).
//   q written PRE-SCALED by 0.125 (exact in bf16); k,v plain; vT transposed v.
// ---------------------------------------------------------------------------
__global__ __launch_bounds__(256)
void gemm_qkv(const ushort_t* __restrict__ A, const ushort_t* __restrict__ Bm,
              ushort_t* __restrict__ q, ushort_t* __restrict__ k,
              ushort_t* __restrict__ v, ushort_t* __restrict__ vT) {
    // XCD decode: 1728 blocks = 8 xcd x (24 n x 9 m_local)
    const int lin = blockIdx.x;
    const int xcd = lin & 7;
    const int j = lin >> 3;            // 0..215
    const int m_local = j % 9;         // m fastest within XCD
    const int n_idx = j / 9;           // 0..23
    const int m_idx = xcd * 9 + m_local;  // 0..71
    if (m_idx >= 65) return;
    const int m0 = m_idx * 128, n0 = n_idx * 128;

    __shared__ ushort_t As[128 * 32];
    __shared__ ushort_t Bs[128 * 32];
    const int tid = threadIdx.x;
    const int wave = tid >> 6, lane = tid & 63;
    const int quad = lane >> 4, l16 = lane & 15;
    const int wm = (wave & 1) * 64, wn = (wave >> 1) * 64;

    const int col8 = (tid & 3) * 8;
    const int row0 = tid >> 2;
    const int ar0 = min(m0 + row0,      M_QKV - 1);
    const int ar1 = min(m0 + row0 + 64, M_QKV - 1);
    const ushort_t* ga0 = A + (size_t)ar0 * K_ + col8;
    const ushort_t* ga1 = A + (size_t)ar1 * K_ + col8;
    const ushort_t* gb0 = Bm + (size_t)(n0 + row0) * K_ + col8;
    const ushort_t* gb1 = Bm + (size_t)(n0 + row0 + 64) * K_ + col8;
    ushort_t* lA0 = As + tid * 8;
    ushort_t* lA1 = As + (tid + 256) * 8;
    ushort_t* lB0 = Bs + tid * 8;
    ushort_t* lB1 = Bs + (tid + 256) * 8;

    f32x4 acc[4][4] = {};

    for (int k0 = 0; k0 < K_; k0 += 32) {
        __syncthreads();
        gload16(ga0 + k0, lA0);
        gload16(ga1 + k0, lA1);
        gload16(gb0 + k0, lB0);
        gload16(gb1 + k0, lB1);
        __syncthreads();
        bf16x8 af[4], bfr[4];
#pragma unroll
        for (int i = 0; i < 4; i++) {
            af[i]  = *(const bf16x8*)(As + (wm + i * 16 + l16) * 32 + quad * 8);
            bfr[i] = *(const bf16x8*)(Bs + (wn + i * 16 + l16) * 32 + quad * 8);
        }
#pragma unroll
        for (int im = 0; im < 4; im++)
#pragma unroll
            for (int in = 0; in < 4; in++)
                acc[im][in] = __builtin_amdgcn_mfma_f32_16x16x32_bf16(af[im], bfr[in], acc[im][in], 0, 0, 0);
    }

#pragma unroll
    for (int im = 0; im < 4; im++) {
#pragma unroll
        for (int in = 0; in < 4; in++) {
            const int gcol = n0 + wn + in * 16 + l16;     // 0..3071
            const int which = gcol >> 10;                 // 0/1/2
            const int c = gcol & 1023;
            const int h = c >> 6, d = c & 63;
            ushort_t* dst = which == 0 ? q : (which == 1 ? k : v);
            const float sc = (which == 0) ? 0.125f : 1.0f;  // pre-scale q
#pragma unroll
            for (int r = 0; r < 4; r++) {
                const int grow = m0 + wm + im * 16 + quad * 4 + r;
                if (grow < M_QKV) {
                    const int b = grow / N_;
                    const int nn = grow - b * N_;
                    const ushort_t val = f2bf(acc[im][in][r] * sc);
                    const size_t bh = (size_t)(b * H_ + h);
                    dst[(bh * N_ + nn) * HD + d] = val;
                    if (which == 2)
                        vT[(bh * HD + d) * NT + nn] = val;
                }
            }
        }
    }
}

// ---------------------------------------------------------------------------
// Attention (best: ~136 us). Swapped QK^T (packed ds_write_b64 P-stores,
// lane-local row-sums), XCD-swizzled grid, dbuf global_load_lds, __expf
// (libm exp2f regressed +33us, r5), NO Vt register hoist (r7 spill),
// Td STAYS LDS-staged (r13: de-staging cost 5x — scratch + L1 thrash).
// Remaining floor: VALU softmax (52% VALUBusy) — needs the full in-register
// T12 path (permlane redistribution) to move, out of scope this session.
// ---------------------------------------------------------------------------
__global__ __launch_bounds__(512, 4)
void attn_kernel(const ushort_t* __restrict__ q, const ushort_t* __restrict__ k,
                 const ushort_t* __restrict__ v, const ushort_t* __restrict__ vT,
                 ushort_t* __restrict__ xvv, ushort_t* __restrict__ xori) {
    __shared__ ushort_t Kd[2][64 * 64];   // k tile [key][dim], swizzled
    __shared__ ushort_t Vd[2][64 * 64];   // v tile [key][dim], swizzled
    __shared__ ushort_t Td[2][64 * 64];   // v^T tile [dim][key], swizzled
    __shared__ ushort_t Ps[8 * 16 * 64];  // [wave][qrow][key], chunk-swizzled

    const int tid = threadIdx.x;
    const int wave = tid >> 6, lane = tid & 63;
    const int quad = lane >> 4, l16 = lane & 15;

    // XCD-aware decode: lin = (bh&7) + 8*((bh>>3)*9 + qt)  [bijective]
    const int lin = blockIdx.x;
    const int r8 = lin & 7;
    const int j = lin >> 3;            // 0..143
    const int g = j / 9;               // 0..15
    const int qt = j - g * 9;          // 0..8
    const int bh = g * 8 + r8;         // 0..127
    const int b = bh >> 4, h = bh & 15;

    const size_t base  = (size_t)bh * N_ * HD;
    const size_t baseT = (size_t)bh * HD * NT;
    const int qstart = min(qt * 128, N_ - 128);
    const int qr0 = qstart + wave * 16;

    // swizzle constants
    const int swz  = (l16 & 7) << 3;      // tile fragment-read XOR (ushort units)
    const int a7   = l16 & 7;             // Ps chunk XOR
    const int prow = (wave * 16 + l16) * 64;  // Ps row base (ushort units)
    const int kq4  = quad * 4;            // per-lane key sub-offset

    // staging geometry: 512 threads cover one 16B chunk per array each
    const int srow = tid >> 3;                       // 0..63
    const int scol = 8 * ((tid & 7) ^ (srow & 7));   // pre-swizzled source col (us)
    const int ld = tid * 8;                          // LDS dest offset (us)

    // Q fragments (always in-bounds); B-operand role (cols = q-rows)
    bf16x8 qq[2], qv[2];
    {
        const int qrow = qr0 + l16;
#pragma unroll
        for (int kk = 0; kk < 2; kk++) {
            U4 uq, uv;
            uq.v = *(const uint4*)(q + base + (size_t)qrow * HD + kk * 32 + quad * 8);
            uv.v = *(const uint4*)(v + base + (size_t)qrow * HD + kk * 32 + quad * 8);
            qq[kk] = *(const bf16x8*)uq.s;
            qv[kk] = *(const bf16x8*)uv.s;
        }
    }

    float l0 = 0.f, l1 = 0.f;          // row-sum for qrow l16 (this quad's keys)
    f32x4 o0[4] = {}, o1[4] = {};

    const int nkt = (N_ + 63) / 64;   // 17

    // ---- prologue: stage tile 0 into buffer 0 (keys 0..63 all valid) ----
    gload16(k + base + (size_t)srow * HD + scol,   &Kd[0][ld]);
    gload16(v + base + (size_t)srow * HD + scol,   &Vd[0][ld]);
    gload16(vT + baseT + (size_t)srow * NT + scol, &Td[0][ld]);

    for (int kt = 0; kt < nkt; kt++) {
        const int key0 = kt * 64;
        const bool tail = (key0 + 64 > N_);
        const int cur = kt & 1;

        __syncthreads();   // implicit vmcnt(0): stage(kt) landed; buf[cur^1] free

        // ---- issue next-tile stage into the other buffer (async DMA) ----
        if (kt + 1 < nkt) {
            const int kn = key0 + 64;
            const int nb = cur ^ 1;
            const int kk0 = min(kn + srow, N_ - 1);       // clamp: masked -> P=0
            gload16(k + base + (size_t)kk0 * HD + scol, &Kd[nb][ld]);
            gload16(v + base + (size_t)kk0 * HD + scol, &Vd[nb][ld]);
            gload16(vT + baseT + (size_t)srow * NT + kn + scol, &Td[nb][ld]);
        }

        const ushort_t* Kc = Kd[cur];
        const ushort_t* Vc = Vd[cur];
        const ushort_t* Tc = Td[cur];

        // ---- path 0: S^T = K·(q/8)^T  (swapped operands) ----
        f32x4 s[4];
        __builtin_amdgcn_s_setprio(1);
#pragma unroll
        for (int t = 0; t < 4; t++) {
            const int row = (t * 16 + l16) * 64;
            bf16x8 b0 = *(const bf16x8*)(Kc + row + ((quad * 8) ^ swz));
            bf16x8 b1 = *(const bf16x8*)(Kc + row + ((32 + quad * 8) ^ swz));
            f32x4 a = {};
            a = __builtin_amdgcn_mfma_f32_16x16x32_bf16(b0, qq[0], a, 0, 0, 0);
            a = __builtin_amdgcn_mfma_f32_16x16x32_bf16(b1, qq[1], a, 0, 0, 0);
            s[t] = a;   // s[t][r] = S[key0+t*16+quad*4+r][qrow=l16]
        }
        __builtin_amdgcn_s_setprio(0);

        if (tail) {
#pragma unroll
            for (int t = 0; t < 4; t++)
#pragma unroll
                for (int r = 0; r < 4; r++)
                    if (key0 + t * 16 + kq4 + r >= N_) s[t][r] = -1e30f;
        }
#pragma unroll
        for (int t = 0; t < 4; t++) {
            const float p0 = __expf(s[t][0]);
            const float p1 = __expf(s[t][1]);
            const float p2 = __expf(s[t][2]);
            const float p3 = __expf(s[t][3]);
            l0 += (p0 + p1) + (p2 + p3);
            *(uint2*)(&Ps[prow + (((t * 4 + quad) >> 1) ^ a7) * 8 + (quad & 1) * 4]) =
                make_uint2(pk2(p0, p1), pk2(p2, p3));
        }
        {
            bf16x8 pa0 = *(const bf16x8*)(&Ps[prow + ((quad    ) ^ a7) * 8]);
            bf16x8 pa1 = *(const bf16x8*)(&Ps[prow + ((quad + 4) ^ a7) * 8]);
            __builtin_amdgcn_s_setprio(1);
#pragma unroll
            for (int t = 0; t < 4; t++) {
                const int row = (t * 16 + l16) * 64;
                bf16x8 bv0 = *(const bf16x8*)(Tc + row + ((quad * 8) ^ swz));
                bf16x8 bv1 = *(const bf16x8*)(Tc + row + ((32 + quad * 8) ^ swz));
                o0[t] = __builtin_amdgcn_mfma_f32_16x16x32_bf16(pa0, bv0, o0[t], 0, 0, 0);
                o0[t] = __builtin_amdgcn_mfma_f32_16x16x32_bf16(pa1, bv1, o0[t], 0, 0, 0);
            }
            __builtin_amdgcn_s_setprio(0);
        }

        // ---- path 1: S^T = V·v^T / 8  (swapped operands) ----
        __builtin_amdgcn_s_setprio(1);
#pragma unroll
        for (int t = 0; t < 4; t++) {
            const int row = (t * 16 + l16) * 64;
            bf16x8 b0 = *(const bf16x8*)(Vc + row + ((quad * 8) ^ swz));
            bf16x8 b1 = *(const bf16x8*)(Vc + row + ((32 + quad * 8) ^ swz));
            f32x4 a = {};
            a = __builtin_amdgcn_mfma_f32_16x16x32_bf16(b0, qv[0], a, 0, 0, 0);
            a = __builtin_amdgcn_mfma_f32_16x16x32_bf16(b1, qv[1], a, 0, 0, 0);
            s[t] = a;
        }
        __builtin_amdgcn_s_setprio(0);
        if (tail) {
#pragma unroll
            for (int t = 0; t < 4; t++)
#pragma unroll
                for (int r = 0; r < 4; r++)
                    if (key0 + t * 16 + kq4 + r >= N_) s[t][r] = -1e30f;
        }
#pragma unroll
        for (int t = 0; t < 4; t++) {
            const float p0 = __expf(s[t][0] * 0.125f);
            const float p1 = __expf(s[t][1] * 0.125f);
            const float p2 = __expf(s[t][2] * 0.125f);
            const float p3 = __expf(s[t][3] * 0.125f);
            l1 += (p0 + p1) + (p2 + p3);
            *(uint2*)(&Ps[prow + (((t * 4 + quad) >> 1) ^ a7) * 8 + (quad & 1) * 4]) =
                make_uint2(pk2(p0, p1), pk2(p2, p3));
        }
        {
            bf16x8 pa0 = *(const bf16x8*)(&Ps[prow + ((quad    ) ^ a7) * 8]);
            bf16x8 pa1 = *(const bf16x8*)(&Ps[prow + ((quad + 4) ^ a7) * 8]);
            __builtin_amdgcn_s_setprio(1);
#pragma unroll
            for (int t = 0; t < 4; t++) {
                const int row = (t * 16 + l16) * 64;
                bf16x8 bv0 = *(const bf16x8*)(Tc + row + ((quad * 8) ^ swz));
                bf16x8 bv1 = *(const bf16x8*)(Tc + row + ((32 + quad * 8) ^ swz));
                o1[t] = __builtin_amdgcn_mfma_f32_16x16x32_bf16(pa0, bv0, o1[t], 0, 0, 0);
                o1[t] = __builtin_amdgcn_mfma_f32_16x16x32_bf16(pa1, bv1, o1[t], 0, 0, 0);
            }
            __builtin_amdgcn_s_setprio(0);
        }
    }

    // ---- epilogue ----
    l0 += __shfl_xor(l0, 16);
    l0 += __shfl_xor(l0, 32);
    l1 += __shfl_xor(l1, 16);
    l1 += __shfl_xor(l1, 32);
#pragma unroll
    for (int r = 0; r < 4; r++) {
        const float inv0 = 1.0f / __shfl(l0, kq4 + r);   // L(qrow=quad*4+r)
        const float inv1 = 1.0f / __shfl(l1, kq4 + r);
        const int row = qr0 + kq4 + r;
        const size_t rb = (size_t)(b * N_ + row) * C_ + h * HD;
#pragma unroll
        for (int t = 0; t < 4; t++) {
            const int d = t * 16 + l16;
            xori[rb + d] = f2bf(o0[t][r] * inv0);
            xvv[rb + d]  = f2bf(o1[t][r] * inv1);
        }
    }
}

// ---------------------------------------------------------------------------
// GEMM 2: OUT(f32) = Xcat(bf16) * Wbf^T + bias. Two-barrier K-loop +
// XCD-aware 1-D grid (r10).
// ---------------------------------------------------------------------------
__global__ __launch_bounds__(256)
void gemm_proj(const ushort_t* __restrict__ A, const ushort_t* __restrict__ Bm,
               const float* __restrict__ bias, float* __restrict__ out) {
    const int lin = blockIdx.x;
    const int xcd = lin & 7;
    const int j = lin >> 3;             // 0..135
    const int m_local = j % 17;         // m fastest within XCD
    const int n_idx = j / 17;           // 0..7
    const int m_idx = xcd * 17 + m_local;  // 0..135
    if (m_idx >= 129) return;
    const int m0 = m_idx * 128, n0 = n_idx * 128;

    __shared__ ushort_t As[128 * 32];
    __shared__ ushort_t Bs[128 * 32];
    const int tid = threadIdx.x;
    const int wave = tid >> 6, lane = tid & 63;
    const int quad = lane >> 4, l16 = lane & 15;
    const int wm = (wave & 1) * 64, wn = (wave >> 1) * 64;

    const int col8 = (tid & 3) * 8;
    const int row0 = tid >> 2;
    const int ar0 = min(m0 + row0,      M_PROJ - 1);
    const int ar1 = min(m0 + row0 + 64, M_PROJ - 1);
    const ushort_t* ga0 = A + (size_t)ar0 * K_ + col8;
    const ushort_t* ga1 = A + (size_t)ar1 * K_ + col8;
    const ushort_t* gb0 = Bm + (size_t)(n0 + row0) * K_ + col8;
    const ushort_t* gb1 = Bm + (size_t)(n0 + row0 + 64) * K_ + col8;
    ushort_t* lA0 = As + tid * 8;
    ushort_t* lA1 = As + (tid + 256) * 8;
    ushort_t* lB0 = Bs + tid * 8;
    ushort_t* lB1 = Bs + (tid + 256) * 8;

    f32x4 acc[4][4] = {};

    for (int k0 = 0; k0 < K_; k0 += 32) {
        __syncthreads();
        gload16(ga0 + k0, lA0);
        gload16(ga1 + k0, lA1);
        gload16(gb0 + k0, lB0);
        gload16(gb1 + k0, lB1);
        __syncthreads();
        bf16x8 af[4], bfr[4];
#pragma unroll
        for (int i = 0; i < 4; i++) {
            af[i]  = *(const bf16x8*)(As + (wm + i * 16 + l16) * 32 + quad * 8);
            bfr[i] = *(const bf16x8*)(Bs + (wn + i * 16 + l16) * 32 + quad * 8);
        }
#pragma unroll
        for (int im = 0; im < 4; im++)
#pragma unroll
            for (int in = 0; in < 4; in++)
                acc[im][in] = __builtin_amdgcn_mfma_f32_16x16x32_bf16(af[im], bfr[in], acc[im][in], 0, 0, 0);
    }

#pragma unroll
    for (int im = 0; im < 4; im++) {
#pragma unroll
        for (int in = 0; in < 4; in++) {
            const int gcol = n0 + wn + in * 16 + l16;
            const float bb = bias[gcol];
#pragma unroll
            for (int r = 0; r < 4; r++) {
                const int grow = m0 + wm + im * 16 + quad * 4 + r;
                if (grow < M_PROJ)
                    out[(size_t)grow * C_ + gcol] = acc[im][in][r] + bb;
            }
        }
    }
}

// ---------------------------------------------------------------------------
// Memory map:
//   d_ws  [0,S1)      : x_bf (phase 1), then xvv   [aliased]
//   d_ws  [S1,2S1)    : xori
//   d_ws  [2S1,3S1)   : v (phases 1-3), then wproj_bf [aliased, conv after attn]
//   d_out [0,S1)      : q (pre-scaled 1/8)   [dead before proj writes]
//   d_out [S1,2S1)    : k
//   d_out [2S1,2S1+VT): vT
//   d_out [2S1+VT,..) : wqkv_bf
// ---------------------------------------------------------------------------
extern "C" void kernel_launch(void* const* d_in, const int* in_sizes, int n_in,
                              void* d_out, int out_size, void* d_ws, size_t ws_size,
                              hipStream_t stream) {
    const float* x      = (const float*)d_in[0];
    const float* w_qkv  = (const float*)d_in[1];
    const float* w_proj = (const float*)d_in[2];
    const float* b_proj = (const float*)d_in[3];
    float* out = (float*)d_out;

    ushort_t* ws = (ushort_t*)d_ws;
    ushort_t* x_bf     = ws;
    ushort_t* xvv      = ws;
    ushort_t* xori     = ws + S1;
    ushort_t* v        = ws + 2 * S1;
    ushort_t* wproj_bf = ws + 2 * S1;

    ushort_t* q        = (ushort_t*)d_out;
    ushort_t* k        = (ushort_t*)d_out + S1;
    ushort_t* vT       = (ushort_t*)d_out + 2 * S1;
    ushort_t* wqkv_bf  = (ushort_t*)d_out + 2 * S1 + VT_SZ;

    {
        const int n8x = (int)(S1 / 8);
        const int n8w = 3 * C_ * C_ / 8;
        conv_bf16_2<<<(n8x + n8w + 255) / 256, 256, 0, stream>>>(
            x, x_bf, n8x, w_qkv, wqkv_bf, n8w);
    }
    {
        gemm_qkv<<<dim3(8 * 24 * 9), 256, 0, stream>>>(x_bf, wqkv_bf, q, k, v, vT);
    }
    {
        attn_kernel<<<dim3(9 * B_ * H_), 512, 0, stream>>>(q, k, v, vT, xvv, xori);
    }
    {
        const int n8p = C_ * C_ / 8;
        conv_bf16<<<(n8p + 255) / 256, 256, 0, stream>>>(w_proj, wproj_bf, n8p);
    }
    {
        gemm_proj<<<dim3(8 * 8 * 17), 256, 0, stream>>>(xvv, wproj_bf, b_proj, out);
    }
}

// Round 17
// 374.613 us; speedup vs baseline: 1.0174x; 1.0045x over previous
//
#include <hip/hip_runtime.h>

typedef unsigned short ushort_t;
typedef __attribute__((ext_vector_type(8))) __bf16 bf16x8;
typedef __attribute__((ext_vector_type(4))) float f32x4;

constexpr int B_ = 8, N_ = 1025, C_ = 1024, H_ = 16, HD = 64;
constexpr int M_QKV = B_ * N_;          // 8200
constexpr int M_PROJ = 2 * B_ * N_;     // 16400
constexpr int K_ = 1024;
constexpr int NT = 1032;                // vT row stride (16B-aligned)
constexpr size_t S1 = (size_t)B_ * H_ * N_ * HD;    // 8,396,800
constexpr size_t VT_SZ = (size_t)B_ * H_ * HD * NT; // 8,454,144

// 0.125 * log2(e): q/qv pre-scale so softmax uses raw 2^x (v_exp_f32).
#define QSCALE 0.18033688f

__device__ __forceinline__ ushort_t f2bf(float f) {
    union { float f; unsigned u; } a; a.f = f;
    unsigned r = a.u + 0x7FFFu + ((a.u >> 16) & 1u);
    return (ushort_t)(r >> 16);
}
__device__ __forceinline__ unsigned pk2(float x, float y) {
    unsigned a = __float_as_uint(x) + 0x8000u;
    unsigned b = __float_as_uint(y) + 0x8000u;
    return (a >> 16) | (b & 0xffff0000u);
}
__device__ __forceinline__ uint4 pack8(float4 x, float4 y) {
    return make_uint4(pk2(x.x, x.y), pk2(x.z, x.w), pk2(y.x, y.y), pk2(y.z, y.w));
}

// Raw hardware exp2: v_exp_f32 computes 2^x natively, no libm denorm fixup
// (r5: __ocml_exp2_f32's fixup tail cost +33us). Guarded fallback stays correct.
#if __has_builtin(__builtin_amdgcn_exp2f)
__device__ __forceinline__ float fexp2(float x) { return __builtin_amdgcn_exp2f(x); }
#else
__device__ __forceinline__ float fexp2(float x) { return __expf(x * 0.69314718f); }
#endif

union U4 { uint4 v; ushort_t s[8]; };

__device__ __forceinline__ void gload16(const ushort_t* g, ushort_t* l) {
    __builtin_amdgcn_global_load_lds(
        (const __attribute__((address_space(1))) void*)g,
        (__attribute__((address_space(3))) void*)l, 16, 0, 0);
}

// ---------------------------------------------------------------------------
__global__ __launch_bounds__(256)
void conv_bf16(const float* __restrict__ src, ushort_t* __restrict__ dst, int n8) {
    const int i = blockIdx.x * 256 + threadIdx.x;
    if (i < n8) {
        const float4* s = (const float4*)src + 2 * (size_t)i;
        ((uint4*)dst)[i] = pack8(s[0], s[1]);
    }
}

// Merged x + w_qkv conversion (one launch instead of two).
__global__ __launch_bounds__(256)
void conv_bf16_2(const float* __restrict__ s1, ushort_t* __restrict__ d1, int n1,
                 const float* __restrict__ s2, ushort_t* __restrict__ d2, int n2) {
    const int i = blockIdx.x * 256 + threadIdx.x;
    if (i < n1) {
        const float4* s = (const float4*)s1 + 2 * (size_t)i;
        ((uint4*)d1)[i] = pack8(s[0], s[1]);
    } else if (i - n1 < n2) {
        const int j = i - n1;
        const float4* s = (const float4*)s2 + 2 * (size_t)j;
        ((uint4*)d2)[j] = pack8(s[0], s[1]);
    }
}

// ---------------------------------------------------------------------------
// GEMM 1: QKV = Xbf * Wbf^T, 128x128x32 tiles. Two-barrier m97 K-loop
// (r9/r11/r15 grafts all null — at the m97-structure ceiling for this shape)
// + XCD-aware 1-D grid (r10).
//   q written PRE-SCALED by 0.125*log2e (attn uses raw exp2); k,v plain;
//   vT transposed v.
// ---------------------------------------------------------------------------
__global__ __launch_bounds__(256)
void gemm_qkv(const ushort_t* __restrict__ A, const ushort_t* __restrict__ Bm,
              ushort_t* __restrict__ q, ushort_t* __restrict__ k,
              ushort_t* __restrict__ v, ushort_t* __restrict__ vT) {
    // XCD decode: 1728 blocks = 8 xcd x (24 n x 9 m_local)
    const int lin = blockIdx.x;
    const int xcd = lin & 7;
    const int j = lin >> 3;            // 0..215
    const int m_local = j % 9;         // m fastest within XCD
    const int n_idx = j / 9;           // 0..23
    const int m_idx = xcd * 9 + m_local;  // 0..71
    if (m_idx >= 65) return;
    const int m0 = m_idx * 128, n0 = n_idx * 128;

    __shared__ ushort_t As[128 * 32];
    __shared__ ushort_t Bs[128 * 32];
    const int tid = threadIdx.x;
    const int wave = tid >> 6, lane = tid & 63;
    const int quad = lane >> 4, l16 = lane & 15;
    const int wm = (wave & 1) * 64, wn = (wave >> 1) * 64;

    const int col8 = (tid & 3) * 8;
    const int row0 = tid >> 2;
    const int ar0 = min(m0 + row0,      M_QKV - 1);
    const int ar1 = min(m0 + row0 + 64, M_QKV - 1);
    const ushort_t* ga0 = A + (size_t)ar0 * K_ + col8;
    const ushort_t* ga1 = A + (size_t)ar1 * K_ + col8;
    const ushort_t* gb0 = Bm + (size_t)(n0 + row0) * K_ + col8;
    const ushort_t* gb1 = Bm + (size_t)(n0 + row0 + 64) * K_ + col8;
    ushort_t* lA0 = As + tid * 8;
    ushort_t* lA1 = As + (tid + 256) * 8;
    ushort_t* lB0 = Bs + tid * 8;
    ushort_t* lB1 = Bs + (tid + 256) * 8;

    f32x4 acc[4][4] = {};

    for (int k0 = 0; k0 < K_; k0 += 32) {
        __syncthreads();
        gload16(ga0 + k0, lA0);
        gload16(ga1 + k0, lA1);
        gload16(gb0 + k0, lB0);
        gload16(gb1 + k0, lB1);
        __syncthreads();
        bf16x8 af[4], bfr[4];
#pragma unroll
        for (int i = 0; i < 4; i++) {
            af[i]  = *(const bf16x8*)(As + (wm + i * 16 + l16) * 32 + quad * 8);
            bfr[i] = *(const bf16x8*)(Bs + (wn + i * 16 + l16) * 32 + quad * 8);
        }
#pragma unroll
        for (int im = 0; im < 4; im++)
#pragma unroll
            for (int in = 0; in < 4; in++)
                acc[im][in] = __builtin_amdgcn_mfma_f32_16x16x32_bf16(af[im], bfr[in], acc[im][in], 0, 0, 0);
    }

#pragma unroll
    for (int im = 0; im < 4; im++) {
#pragma unroll
        for (int in = 0; in < 4; in++) {
            const int gcol = n0 + wn + in * 16 + l16;     // 0..3071
            const int which = gcol >> 10;                 // 0/1/2
            const int c = gcol & 1023;
            const int h = c >> 6, d = c & 63;
            ushort_t* dst = which == 0 ? q : (which == 1 ? k : v);
            const float sc = (which == 0) ? QSCALE : 1.0f;  // pre-scale q
#pragma unroll
            for (int r = 0; r < 4; r++) {
                const int grow = m0 + wm + im * 16 + quad * 4 + r;
                if (grow < M_QKV) {
                    const int b = grow / N_;
                    const int nn = grow - b * N_;
                    const ushort_t val = f2bf(acc[im][in][r] * sc);
                    const size_t bh = (size_t)(b * H_ + h);
                    dst[(bh * N_ + nn) * HD + d] = val;
                    if (which == 2)
                        vT[(bh * HD + d) * NT + nn] = val;
                }
            }
        }
    }
}

// ---------------------------------------------------------------------------
// Attention (r16 base, ~138 us). Swapped QK^T, packed P-stores, lane-local
// sums, XCD swizzle, dbuf gload_lds, Td LDS-staged (r13: de-staging = 5x).
// NEW (r17): all softmax scale-muls removed — q pre-scaled by 0.125*log2e in
// gemm, qv fragments pre-scaled once at load, exp = raw v_exp_f32 (2^x).
// Saves 96 of ~295 VALU ops/tile/lane.
// ---------------------------------------------------------------------------
__global__ __launch_bounds__(512, 4)
void attn_kernel(const ushort_t* __restrict__ q, const ushort_t* __restrict__ k,
                 const ushort_t* __restrict__ v, const ushort_t* __restrict__ vT,
                 ushort_t* __restrict__ xvv, ushort_t* __restrict__ xori) {
    __shared__ ushort_t Kd[2][64 * 64];   // k tile [key][dim], swizzled
    __shared__ ushort_t Vd[2][64 * 64];   // v tile [key][dim], swizzled
    __shared__ ushort_t Td[2][64 * 64];   // v^T tile [dim][key], swizzled
    __shared__ ushort_t Ps[8 * 16 * 64];  // [wave][qrow][key], chunk-swizzled

    const int tid = threadIdx.x;
    const int wave = tid >> 6, lane = tid & 63;
    const int quad = lane >> 4, l16 = lane & 15;

    // XCD-aware decode: lin = (bh&7) + 8*((bh>>3)*9 + qt)  [bijective]
    const int lin = blockIdx.x;
    const int r8 = lin & 7;
    const int j = lin >> 3;            // 0..143
    const int g = j / 9;               // 0..15
    const int qt = j - g * 9;          // 0..8
    const int bh = g * 8 + r8;         // 0..127
    const int b = bh >> 4, h = bh & 15;

    const size_t base  = (size_t)bh * N_ * HD;
    const size_t baseT = (size_t)bh * HD * NT;
    const int qstart = min(qt * 128, N_ - 128);
    const int qr0 = qstart + wave * 16;

    // swizzle constants
    const int swz  = (l16 & 7) << 3;      // tile fragment-read XOR (ushort units)
    const int a7   = l16 & 7;             // Ps chunk XOR
    const int prow = (wave * 16 + l16) * 64;  // Ps row base (ushort units)
    const int kq4  = quad * 4;            // per-lane key sub-offset

    // staging geometry: 512 threads cover one 16B chunk per array each
    const int srow = tid >> 3;                       // 0..63
    const int scol = 8 * ((tid & 7) ^ (srow & 7));   // pre-swizzled source col (us)
    const int ld = tid * 8;                          // LDS dest offset (us)

    // Q fragments; qq arrives pre-scaled from gemm, qv scaled here (once).
    bf16x8 qq[2], qv[2];
    {
        const int qrow = qr0 + l16;
#pragma unroll
        for (int kk = 0; kk < 2; kk++) {
            U4 uq, uv, us;
            uq.v = *(const uint4*)(q + base + (size_t)qrow * HD + kk * 32 + quad * 8);
            uv.v = *(const uint4*)(v + base + (size_t)qrow * HD + kk * 32 + quad * 8);
#pragma unroll
            for (int e = 0; e < 8; e += 2) {
                const float f0 = __uint_as_float((unsigned)uv.s[e]     << 16) * QSCALE;
                const float f1 = __uint_as_float((unsigned)uv.s[e + 1] << 16) * QSCALE;
                ((unsigned*)&us.v)[e >> 1] = pk2(f0, f1);
            }
            qq[kk] = *(const bf16x8*)uq.s;
            qv[kk] = *(const bf16x8*)us.s;
        }
    }

    float l0 = 0.f, l1 = 0.f;          // row-sum for qrow l16 (this quad's keys)
    f32x4 o0[4] = {}, o1[4] = {};

    const int nkt = (N_ + 63) / 64;   // 17

    // ---- prologue: stage tile 0 into buffer 0 (keys 0..63 all valid) ----
    gload16(k + base + (size_t)srow * HD + scol,   &Kd[0][ld]);
    gload16(v + base + (size_t)srow * HD + scol,   &Vd[0][ld]);
    gload16(vT + baseT + (size_t)srow * NT + scol, &Td[0][ld]);

    for (int kt = 0; kt < nkt; kt++) {
        const int key0 = kt * 64;
        const bool tail = (key0 + 64 > N_);
        const int cur = kt & 1;

        __syncthreads();   // implicit vmcnt(0): stage(kt) landed; buf[cur^1] free

        // ---- issue next-tile stage into the other buffer (async DMA) ----
        if (kt + 1 < nkt) {
            const int kn = key0 + 64;
            const int nb = cur ^ 1;
            const int kk0 = min(kn + srow, N_ - 1);       // clamp: masked -> P=0
            gload16(k + base + (size_t)kk0 * HD + scol, &Kd[nb][ld]);
            gload16(v + base + (size_t)kk0 * HD + scol, &Vd[nb][ld]);
            gload16(vT + baseT + (size_t)srow * NT + kn + scol, &Td[nb][ld]);
        }

        const ushort_t* Kc = Kd[cur];
        const ushort_t* Vc = Vd[cur];
        const ushort_t* Tc = Td[cur];

        // ---- path 0: S^T = K·(q*0.125*log2e)^T  (swapped operands) ----
        f32x4 s[4];
        __builtin_amdgcn_s_setprio(1);
#pragma unroll
        for (int t = 0; t < 4; t++) {
            const int row = (t * 16 + l16) * 64;
            bf16x8 b0 = *(const bf16x8*)(Kc + row + ((quad * 8) ^ swz));
            bf16x8 b1 = *(const bf16x8*)(Kc + row + ((32 + quad * 8) ^ swz));
            f32x4 a = {};
            a = __builtin_amdgcn_mfma_f32_16x16x32_bf16(b0, qq[0], a, 0, 0, 0);
            a = __builtin_amdgcn_mfma_f32_16x16x32_bf16(b1, qq[1], a, 0, 0, 0);
            s[t] = a;   // s[t][r] = S2[key0+t*16+quad*4+r][qrow=l16] (log2 domain)
        }
        __builtin_amdgcn_s_setprio(0);

        if (tail) {
#pragma unroll
            for (int t = 0; t < 4; t++)
#pragma unroll
                for (int r = 0; r < 4; r++)
                    if (key0 + t * 16 + kq4 + r >= N_) s[t][r] = -1e30f;
        }
#pragma unroll
        for (int t = 0; t < 4; t++) {
            const float p0 = fexp2(s[t][0]);
            const float p1 = fexp2(s[t][1]);
            const float p2 = fexp2(s[t][2]);
            const float p3 = fexp2(s[t][3]);
            l0 += (p0 + p1) + (p2 + p3);
            *(uint2*)(&Ps[prow + (((t * 4 + quad) >> 1) ^ a7) * 8 + (quad & 1) * 4]) =
                make_uint2(pk2(p0, p1), pk2(p2, p3));
        }
        {
            bf16x8 pa0 = *(const bf16x8*)(&Ps[prow + ((quad    ) ^ a7) * 8]);
            bf16x8 pa1 = *(const bf16x8*)(&Ps[prow + ((quad + 4) ^ a7) * 8]);
            __builtin_amdgcn_s_setprio(1);
#pragma unroll
            for (int t = 0; t < 4; t++) {
                const int row = (t * 16 + l16) * 64;
                bf16x8 bv0 = *(const bf16x8*)(Tc + row + ((quad * 8) ^ swz));
                bf16x8 bv1 = *(const bf16x8*)(Tc + row + ((32 + quad * 8) ^ swz));
                o0[t] = __builtin_amdgcn_mfma_f32_16x16x32_bf16(pa0, bv0, o0[t], 0, 0, 0);
                o0[t] = __builtin_amdgcn_mfma_f32_16x16x32_bf16(pa1, bv1, o0[t], 0, 0, 0);
            }
            __builtin_amdgcn_s_setprio(0);
        }

        // ---- path 1: S^T = V·(v*0.125*log2e)^T  (swapped operands) ----
        __builtin_amdgcn_s_setprio(1);
#pragma unroll
        for (int t = 0; t < 4; t++) {
            const int row = (t * 16 + l16) * 64;
            bf16x8 b0 = *(const bf16x8*)(Vc + row + ((quad * 8) ^ swz));
            bf16x8 b1 = *(const bf16x8*)(Vc + row + ((32 + quad * 8) ^ swz));
            f32x4 a = {};
            a = __builtin_amdgcn_mfma_f32_16x16x32_bf16(b0, qv[0], a, 0, 0, 0);
            a = __builtin_amdgcn_mfma_f32_16x16x32_bf16(b1, qv[1], a, 0, 0, 0);
            s[t] = a;
        }
        __builtin_amdgcn_s_setprio(0);
        if (tail) {
#pragma unroll
            for (int t = 0; t < 4; t++)
#pragma unroll
                for (int r = 0; r < 4; r++)
                    if (key0 + t * 16 + kq4 + r >= N_) s[t][r] = -1e30f;
        }
#pragma unroll
        for (int t = 0; t < 4; t++) {
            const float p0 = fexp2(s[t][0]);
            const float p1 = fexp2(s[t][1]);
            const float p2 = fexp2(s[t][2]);
            const float p3 = fexp2(s[t][3]);
            l1 += (p0 + p1) + (p2 + p3);
            *(uint2*)(&Ps[prow + (((t * 4 + quad) >> 1) ^ a7) * 8 + (quad & 1) * 4]) =
                make_uint2(pk2(p0, p1), pk2(p2, p3));
        }
        {
            bf16x8 pa0 = *(const bf16x8*)(&Ps[prow + ((quad    ) ^ a7) * 8]);
            bf16x8 pa1 = *(const bf16x8*)(&Ps[prow + ((quad + 4) ^ a7) * 8]);
            __builtin_amdgcn_s_setprio(1);
#pragma unroll
            for (int t = 0; t < 4; t++) {
                const int row = (t * 16 + l16) * 64;
                bf16x8 bv0 = *(const bf16x8*)(Tc + row + ((quad * 8) ^ swz));
                bf16x8 bv1 = *(const bf16x8*)(Tc + row + ((32 + quad * 8) ^ swz));
                o1[t] = __builtin_amdgcn_mfma_f32_16x16x32_bf16(pa0, bv0, o1[t], 0, 0, 0);
                o1[t] = __builtin_amdgcn_mfma_f32_16x16x32_bf16(pa1, bv1, o1[t], 0, 0, 0);
            }
            __builtin_amdgcn_s_setprio(0);
        }
    }

    // ---- epilogue ----
    l0 += __shfl_xor(l0, 16);
    l0 += __shfl_xor(l0, 32);
    l1 += __shfl_xor(l1, 16);
    l1 += __shfl_xor(l1, 32);
#pragma unroll
    for (int r = 0; r < 4; r++) {
        const float inv0 = 1.0f / __shfl(l0, kq4 + r);   // L(qrow=quad*4+r)
        const float inv1 = 1.0f / __shfl(l1, kq4 + r);
        const int row = qr0 + kq4 + r;
        const size_t rb = (size_t)(b * N_ + row) * C_ + h * HD;
#pragma unroll
        for (int t = 0; t < 4; t++) {
            const int d = t * 16 + l16;
            xori[rb + d] = f2bf(o0[t][r] * inv0);
            xvv[rb + d]  = f2bf(o1[t][r] * inv1);
        }
    }
}

// ---------------------------------------------------------------------------
// GEMM 2: OUT(f32) = Xcat(bf16) * Wbf^T + bias. Two-barrier K-loop +
// XCD-aware 1-D grid (r10).
// ---------------------------------------------------------------------------
__global__ __launch_bounds__(256)
void gemm_proj(const ushort_t* __restrict__ A, const ushort_t* __restrict__ Bm,
               const float* __restrict__ bias, float* __restrict__ out) {
    const int lin = blockIdx.x;
    const int xcd = lin & 7;
    const int j = lin >> 3;             // 0..135
    const int m_local = j % 17;         // m fastest within XCD
    const int n_idx = j / 17;           // 0..7
    const int m_idx = xcd * 17 + m_local;  // 0..135
    if (m_idx >= 129) return;
    const int m0 = m_idx * 128, n0 = n_idx * 128;

    __shared__ ushort_t As[128 * 32];
    __shared__ ushort_t Bs[128 * 32];
    const int tid = threadIdx.x;
    const int wave = tid >> 6, lane = tid & 63;
    const int quad = lane >> 4, l16 = lane & 15;
    const int wm = (wave & 1) * 64, wn = (wave >> 1) * 64;

    const int col8 = (tid & 3) * 8;
    const int row0 = tid >> 2;
    const int ar0 = min(m0 + row0,      M_PROJ - 1);
    const int ar1 = min(m0 + row0 + 64, M_PROJ - 1);
    const ushort_t* ga0 = A + (size_t)ar0 * K_ + col8;
    const ushort_t* ga1 = A + (size_t)ar1 * K_ + col8;
    const ushort_t* gb0 = Bm + (size_t)(n0 + row0) * K_ + col8;
    const ushort_t* gb1 = Bm + (size_t)(n0 + row0 + 64) * K_ + col8;
    ushort_t* lA0 = As + tid * 8;
    ushort_t* lA1 = As + (tid + 256) * 8;
    ushort_t* lB0 = Bs + tid * 8;
    ushort_t* lB1 = Bs + (tid + 256) * 8;

    f32x4 acc[4][4] = {};

    for (int k0 = 0; k0 < K_; k0 += 32) {
        __syncthreads();
        gload16(ga0 + k0, lA0);
        gload16(ga1 + k0, lA1);
        gload16(gb0 + k0, lB0);
        gload16(gb1 + k0, lB1);
        __syncthreads();
        bf16x8 af[4], bfr[4];
#pragma unroll
        for (int i = 0; i < 4; i++) {
            af[i]  = *(const bf16x8*)(As + (wm + i * 16 + l16) * 32 + quad * 8);
            bfr[i] = *(const bf16x8*)(Bs + (wn + i * 16 + l16) * 32 + quad * 8);
        }
#pragma unroll
        for (int im = 0; im < 4; im++)
#pragma unroll
            for (int in = 0; in < 4; in++)
                acc[im][in] = __builtin_amdgcn_mfma_f32_16x16x32_bf16(af[im], bfr[in], acc[im][in], 0, 0, 0);
    }

#pragma unroll
    for (int im = 0; im < 4; im++) {
#pragma unroll
        for (int in = 0; in < 4; in++) {
            const int gcol = n0 + wn + in * 16 + l16;
            const float bb = bias[gcol];
#pragma unroll
            for (int r = 0; r < 4; r++) {
                const int grow = m0 + wm + im * 16 + quad * 4 + r;
                if (grow < M_PROJ)
                    out[(size_t)grow * C_ + gcol] = acc[im][in][r] + bb;
            }
        }
    }
}

// ---------------------------------------------------------------------------
// Memory map:
//   d_ws  [0,S1)      : x_bf (phase 1), then xvv   [aliased]
//   d_ws  [S1,2S1)    : xori
//   d_ws  [2S1,3S1)   : v (phases 1-3), then wproj_bf [aliased, conv after attn]
//   d_out [0,S1)      : q (pre-scaled 0.125*log2e)   [dead before proj writes]
//   d_out [S1,2S1)    : k
//   d_out [2S1,2S1+VT): vT
//   d_out [2S1+VT,..) : wqkv_bf
// ---------------------------------------------------------------------------
extern "C" void kernel_launch(void* const* d_in, const int* in_sizes, int n_in,
                              void* d_out, int out_size, void* d_ws, size_t ws_size,
                              hipStream_t stream) {
    const float* x      = (const float*)d_in[0];
    const float* w_qkv  = (const float*)d_in[1];
    const float* w_proj = (const float*)d_in[2];
    const float* b_proj = (const float*)d_in[3];
    float* out = (float*)d_out;

    ushort_t* ws = (ushort_t*)d_ws;
    ushort_t* x_bf     = ws;
    ushort_t* xvv      = ws;
    ushort_t* xori     = ws + S1;
    ushort_t* v        = ws + 2 * S1;
    ushort_t* wproj_bf = ws + 2 * S1;

    ushort_t* q        = (ushort_t*)d_out;
    ushort_t* k        = (ushort_t*)d_out + S1;
    ushort_t* vT       = (ushort_t*)d_out + 2 * S1;
    ushort_t* wqkv_bf  = (ushort_t*)d_out + 2 * S1 + VT_SZ;

    {
        const int n8x = (int)(S1 / 8);
        const int n8w = 3 * C_ * C_ / 8;
        conv_bf16_2<<<(n8x + n8w + 255) / 256, 256, 0, stream>>>(
            x, x_bf, n8x, w_qkv, wqkv_bf, n8w);
    }
    {
        gemm_qkv<<<dim3(8 * 24 * 9), 256, 0, stream>>>(x_bf, wqkv_bf, q, k, v, vT);
    }
    {
        attn_kernel<<<dim3(9 * B_ * H_), 512, 0, stream>>>(q, k, v, vT, xvv, xori);
    }
    {
        const int n8p = C_ * C_ / 8;
        conv_bf16<<<(n8p + 255) / 256, 256, 0, stream>>>(w_proj, wproj_bf, n8p);
    }
    {
        gemm_proj<<<dim3(8 * 8 * 17), 256, 0, stream>>>(xvv, wproj_bf, b_proj, out);
    }
}

// Round 18
// 372.975 us; speedup vs baseline: 1.0219x; 1.0044x over previous
//
#include <hip/hip_runtime.h>

typedef unsigned short ushort_t;
typedef __attribute__((ext_vector_type(8))) __bf16 bf16x8;
typedef __attribute__((ext_vector_type(4))) float f32x4;

constexpr int B_ = 8, N_ = 1025, C_ = 1024, H_ = 16, HD = 64;
constexpr int M_QKV = B_ * N_;          // 8200
constexpr int M_PROJ = 2 * B_ * N_;     // 16400
constexpr int K_ = 1024;
constexpr int NT = 1032;                // vT row stride (16B-aligned)
constexpr size_t S1 = (size_t)B_ * H_ * N_ * HD;    // 8,396,800
constexpr size_t VT_SZ = (size_t)B_ * H_ * HD * NT; // 8,454,144

// 0.125 * log2(e): q/qv pre-scale so softmax uses raw 2^x (v_exp_f32).
#define QSCALE 0.18033688f

__device__ __forceinline__ ushort_t f2bf(float f) {
    union { float f; unsigned u; } a; a.f = f;
    unsigned r = a.u + 0x7FFFu + ((a.u >> 16) & 1u);
    return (ushort_t)(r >> 16);
}
__device__ __forceinline__ unsigned pk2(float x, float y) {
    unsigned a = __float_as_uint(x) + 0x8000u;
    unsigned b = __float_as_uint(y) + 0x8000u;
    return (a >> 16) | (b & 0xffff0000u);
}
__device__ __forceinline__ uint4 pack8(float4 x, float4 y) {
    return make_uint4(pk2(x.x, x.y), pk2(x.z, x.w), pk2(y.x, y.y), pk2(y.z, y.w));
}

// Raw hardware exp2: v_exp_f32 computes 2^x natively, no libm denorm fixup
// (r5: __ocml_exp2_f32's fixup tail cost +33us).
#if __has_builtin(__builtin_amdgcn_exp2f)
__device__ __forceinline__ float fexp2(float x) { return __builtin_amdgcn_exp2f(x); }
#else
__device__ __forceinline__ float fexp2(float x) { return __expf(x * 0.69314718f); }
#endif

union U4 { uint4 v; ushort_t s[8]; };

__device__ __forceinline__ void gload16(const ushort_t* g, ushort_t* l) {
    __builtin_amdgcn_global_load_lds(
        (const __attribute__((address_space(1))) void*)g,
        (__attribute__((address_space(3))) void*)l, 16, 0, 0);
}

// ---------------------------------------------------------------------------
__global__ __launch_bounds__(256)
void conv_bf16(const float* __restrict__ src, ushort_t* __restrict__ dst, int n8) {
    const int i = blockIdx.x * 256 + threadIdx.x;
    if (i < n8) {
        const float4* s = (const float4*)src + 2 * (size_t)i;
        ((uint4*)dst)[i] = pack8(s[0], s[1]);
    }
}

// Merged x + w_qkv conversion (one launch instead of two).
__global__ __launch_bounds__(256)
void conv_bf16_2(const float* __restrict__ s1, ushort_t* __restrict__ d1, int n1,
                 const float* __restrict__ s2, ushort_t* __restrict__ d2, int n2) {
    const int i = blockIdx.x * 256 + threadIdx.x;
    if (i < n1) {
        const float4* s = (const float4*)s1 + 2 * (size_t)i;
        ((uint4*)d1)[i] = pack8(s[0], s[1]);
    } else if (i - n1 < n2) {
        const int j = i - n1;
        const float4* s = (const float4*)s2 + 2 * (size_t)j;
        ((uint4*)d2)[j] = pack8(s[0], s[1]);
    }
}

// ---------------------------------------------------------------------------
// GEMM 1: QKV = Xbf * Wbf^T, 128x128x32 tiles. Two-barrier m97 K-loop
// (r9/r11/r15 grafts all null — at the m97-structure ceiling for this shape)
// + XCD-aware 1-D grid (r10).
//   q written PRE-SCALED by 0.125*log2e (attn uses raw exp2); k,v plain;
//   vT transposed v.
// ---------------------------------------------------------------------------
__global__ __launch_bounds__(256)
void gemm_qkv(const ushort_t* __restrict__ A, const ushort_t* __restrict__ Bm,
              ushort_t* __restrict__ q, ushort_t* __restrict__ k,
              ushort_t* __restrict__ v, ushort_t* __restrict__ vT) {
    // XCD decode: 1728 blocks = 8 xcd x (24 n x 9 m_local)
    const int lin = blockIdx.x;
    const int xcd = lin & 7;
    const int j = lin >> 3;            // 0..215
    const int m_local = j % 9;         // m fastest within XCD
    const int n_idx = j / 9;           // 0..23
    const int m_idx = xcd * 9 + m_local;  // 0..71
    if (m_idx >= 65) return;
    const int m0 = m_idx * 128, n0 = n_idx * 128;

    __shared__ ushort_t As[128 * 32];
    __shared__ ushort_t Bs[128 * 32];
    const int tid = threadIdx.x;
    const int wave = tid >> 6, lane = tid & 63;
    const int quad = lane >> 4, l16 = lane & 15;
    const int wm = (wave & 1) * 64, wn = (wave >> 1) * 64;

    const int col8 = (tid & 3) * 8;
    const int row0 = tid >> 2;
    const int ar0 = min(m0 + row0,      M_QKV - 1);
    const int ar1 = min(m0 + row0 + 64, M_QKV - 1);
    const ushort_t* ga0 = A + (size_t)ar0 * K_ + col8;
    const ushort_t* ga1 = A + (size_t)ar1 * K_ + col8;
    const ushort_t* gb0 = Bm + (size_t)(n0 + row0) * K_ + col8;
    const ushort_t* gb1 = Bm + (size_t)(n0 + row0 + 64) * K_ + col8;
    ushort_t* lA0 = As + tid * 8;
    ushort_t* lA1 = As + (tid + 256) * 8;
    ushort_t* lB0 = Bs + tid * 8;
    ushort_t* lB1 = Bs + (tid + 256) * 8;

    f32x4 acc[4][4] = {};

    for (int k0 = 0; k0 < K_; k0 += 32) {
        __syncthreads();
        gload16(ga0 + k0, lA0);
        gload16(ga1 + k0, lA1);
        gload16(gb0 + k0, lB0);
        gload16(gb1 + k0, lB1);
        __syncthreads();
        bf16x8 af[4], bfr[4];
#pragma unroll
        for (int i = 0; i < 4; i++) {
            af[i]  = *(const bf16x8*)(As + (wm + i * 16 + l16) * 32 + quad * 8);
            bfr[i] = *(const bf16x8*)(Bs + (wn + i * 16 + l16) * 32 + quad * 8);
        }
#pragma unroll
        for (int im = 0; im < 4; im++)
#pragma unroll
            for (int in = 0; in < 4; in++)
                acc[im][in] = __builtin_amdgcn_mfma_f32_16x16x32_bf16(af[im], bfr[in], acc[im][in], 0, 0, 0);
    }

#pragma unroll
    for (int im = 0; im < 4; im++) {
#pragma unroll
        for (int in = 0; in < 4; in++) {
            const int gcol = n0 + wn + in * 16 + l16;     // 0..3071
            const int which = gcol >> 10;                 // 0/1/2
            const int c = gcol & 1023;
            const int h = c >> 6, d = c & 63;
            ushort_t* dst = which == 0 ? q : (which == 1 ? k : v);
            const float sc = (which == 0) ? QSCALE : 1.0f;  // pre-scale q
#pragma unroll
            for (int r = 0; r < 4; r++) {
                const int grow = m0 + wm + im * 16 + quad * 4 + r;
                if (grow < M_QKV) {
                    const int b = grow / N_;
                    const int nn = grow - b * N_;
                    const ushort_t val = f2bf(acc[im][in][r] * sc);
                    const size_t bh = (size_t)(b * H_ + h);
                    dst[(bh * N_ + nn) * HD + d] = val;
                    if (which == 2)
                        vT[(bh * HD + d) * NT + nn] = val;
                }
            }
        }
    }
}

// ---------------------------------------------------------------------------
// Attention (r17 base, ~132 us). Swapped QK^T, packed P-stores, XCD swizzle,
// dbuf gload_lds, Td LDS-staged, exp = raw v_exp_f32 on pre-scaled scores.
// NEW (r18): row-sums L = P·1 computed on the MFMA pipe — two extra MFMAs
// per path reuse the already-loaded pa0/pa1 fragments with an all-ones B
// operand. Removes 32 serial v_adds/tile AND the 12-shuffle epilogue
// reduction (C-layout lands L[quad*4+r] in lac[r] on every lane — exactly
// the epilogue distribution). L now sums bf16-rounded P, consistent with
// the PV numerator.
// ---------------------------------------------------------------------------
__global__ __launch_bounds__(512, 4)
void attn_kernel(const ushort_t* __restrict__ q, const ushort_t* __restrict__ k,
                 const ushort_t* __restrict__ v, const ushort_t* __restrict__ vT,
                 ushort_t* __restrict__ xvv, ushort_t* __restrict__ xori) {
    __shared__ ushort_t Kd[2][64 * 64];   // k tile [key][dim], swizzled
    __shared__ ushort_t Vd[2][64 * 64];   // v tile [key][dim], swizzled
    __shared__ ushort_t Td[2][64 * 64];   // v^T tile [dim][key], swizzled
    __shared__ ushort_t Ps[8 * 16 * 64];  // [wave][qrow][key], chunk-swizzled

    const int tid = threadIdx.x;
    const int wave = tid >> 6, lane = tid & 63;
    const int quad = lane >> 4, l16 = lane & 15;

    // XCD-aware decode: lin = (bh&7) + 8*((bh>>3)*9 + qt)  [bijective]
    const int lin = blockIdx.x;
    const int r8 = lin & 7;
    const int j = lin >> 3;            // 0..143
    const int g = j / 9;               // 0..15
    const int qt = j - g * 9;          // 0..8
    const int bh = g * 8 + r8;         // 0..127
    const int b = bh >> 4, h = bh & 15;

    const size_t base  = (size_t)bh * N_ * HD;
    const size_t baseT = (size_t)bh * HD * NT;
    const int qstart = min(qt * 128, N_ - 128);
    const int qr0 = qstart + wave * 16;

    // swizzle constants
    const int swz  = (l16 & 7) << 3;      // tile fragment-read XOR (ushort units)
    const int a7   = l16 & 7;             // Ps chunk XOR
    const int prow = (wave * 16 + l16) * 64;  // Ps row base (ushort units)
    const int kq4  = quad * 4;            // per-lane key sub-offset

    // staging geometry: 512 threads cover one 16B chunk per array each
    const int srow = tid >> 3;                       // 0..63
    const int scol = 8 * ((tid & 7) ^ (srow & 7));   // pre-swizzled source col (us)
    const int ld = tid * 8;                          // LDS dest offset (us)

    // all-ones bf16 B-fragment for the L = P·1 MFMAs
    bf16x8 ones;
    {
        U4 u;
#pragma unroll
        for (int e = 0; e < 8; e++) u.s[e] = 0x3F80;  // bf16 1.0
        ones = *(const bf16x8*)u.s;
    }

    // Q fragments; qq arrives pre-scaled from gemm, qv scaled here (once).
    bf16x8 qq[2], qv[2];
    {
        const int qrow = qr0 + l16;
#pragma unroll
        for (int kk = 0; kk < 2; kk++) {
            U4 uq, uv, us;
            uq.v = *(const uint4*)(q + base + (size_t)qrow * HD + kk * 32 + quad * 8);
            uv.v = *(const uint4*)(v + base + (size_t)qrow * HD + kk * 32 + quad * 8);
#pragma unroll
            for (int e = 0; e < 8; e += 2) {
                const float f0 = __uint_as_float((unsigned)uv.s[e]     << 16) * QSCALE;
                const float f1 = __uint_as_float((unsigned)uv.s[e + 1] << 16) * QSCALE;
                ((unsigned*)&us.v)[e >> 1] = pk2(f0, f1);
            }
            qq[kk] = *(const bf16x8*)uq.s;
            qv[kk] = *(const bf16x8*)us.s;
        }
    }

    f32x4 lac0 = {}, lac1 = {};        // L accumulators (MFMA C-layout)
    f32x4 o0[4] = {}, o1[4] = {};

    const int nkt = (N_ + 63) / 64;   // 17

    // ---- prologue: stage tile 0 into buffer 0 (keys 0..63 all valid) ----
    gload16(k + base + (size_t)srow * HD + scol,   &Kd[0][ld]);
    gload16(v + base + (size_t)srow * HD + scol,   &Vd[0][ld]);
    gload16(vT + baseT + (size_t)srow * NT + scol, &Td[0][ld]);

    for (int kt = 0; kt < nkt; kt++) {
        const int key0 = kt * 64;
        const bool tail = (key0 + 64 > N_);
        const int cur = kt & 1;

        __syncthreads();   // implicit vmcnt(0): stage(kt) landed; buf[cur^1] free

        // ---- issue next-tile stage into the other buffer (async DMA) ----
        if (kt + 1 < nkt) {
            const int kn = key0 + 64;
            const int nb = cur ^ 1;
            const int kk0 = min(kn + srow, N_ - 1);       // clamp: masked -> P=0
            gload16(k + base + (size_t)kk0 * HD + scol, &Kd[nb][ld]);
            gload16(v + base + (size_t)kk0 * HD + scol, &Vd[nb][ld]);
            gload16(vT + baseT + (size_t)srow * NT + kn + scol, &Td[nb][ld]);
        }

        const ushort_t* Kc = Kd[cur];
        const ushort_t* Vc = Vd[cur];
        const ushort_t* Tc = Td[cur];

        // ---- path 0: S^T = K·(q*0.125*log2e)^T  (swapped operands) ----
        f32x4 s[4];
        __builtin_amdgcn_s_setprio(1);
#pragma unroll
        for (int t = 0; t < 4; t++) {
            const int row = (t * 16 + l16) * 64;
            bf16x8 b0 = *(const bf16x8*)(Kc + row + ((quad * 8) ^ swz));
            bf16x8 b1 = *(const bf16x8*)(Kc + row + ((32 + quad * 8) ^ swz));
            f32x4 a = {};
            a = __builtin_amdgcn_mfma_f32_16x16x32_bf16(b0, qq[0], a, 0, 0, 0);
            a = __builtin_amdgcn_mfma_f32_16x16x32_bf16(b1, qq[1], a, 0, 0, 0);
            s[t] = a;   // s[t][r] = S2[key0+t*16+quad*4+r][qrow=l16] (log2 domain)
        }
        __builtin_amdgcn_s_setprio(0);

        if (tail) {
#pragma unroll
            for (int t = 0; t < 4; t++)
#pragma unroll
                for (int r = 0; r < 4; r++)
                    if (key0 + t * 16 + kq4 + r >= N_) s[t][r] = -1e30f;
        }
#pragma unroll
        for (int t = 0; t < 4; t++) {
            const float p0 = fexp2(s[t][0]);
            const float p1 = fexp2(s[t][1]);
            const float p2 = fexp2(s[t][2]);
            const float p3 = fexp2(s[t][3]);
            *(uint2*)(&Ps[prow + (((t * 4 + quad) >> 1) ^ a7) * 8 + (quad & 1) * 4]) =
                make_uint2(pk2(p0, p1), pk2(p2, p3));
        }
        {
            bf16x8 pa0 = *(const bf16x8*)(&Ps[prow + ((quad    ) ^ a7) * 8]);
            bf16x8 pa1 = *(const bf16x8*)(&Ps[prow + ((quad + 4) ^ a7) * 8]);
            __builtin_amdgcn_s_setprio(1);
            lac0 = __builtin_amdgcn_mfma_f32_16x16x32_bf16(pa0, ones, lac0, 0, 0, 0);
            lac0 = __builtin_amdgcn_mfma_f32_16x16x32_bf16(pa1, ones, lac0, 0, 0, 0);
#pragma unroll
            for (int t = 0; t < 4; t++) {
                const int row = (t * 16 + l16) * 64;
                bf16x8 bv0 = *(const bf16x8*)(Tc + row + ((quad * 8) ^ swz));
                bf16x8 bv1 = *(const bf16x8*)(Tc + row + ((32 + quad * 8) ^ swz));
                o0[t] = __builtin_amdgcn_mfma_f32_16x16x32_bf16(pa0, bv0, o0[t], 0, 0, 0);
                o0[t] = __builtin_amdgcn_mfma_f32_16x16x32_bf16(pa1, bv1, o0[t], 0, 0, 0);
            }
            __builtin_amdgcn_s_setprio(0);
        }

        // ---- path 1: S^T = V·(v*0.125*log2e)^T  (swapped operands) ----
        __builtin_amdgcn_s_setprio(1);
#pragma unroll
        for (int t = 0; t < 4; t++) {
            const int row = (t * 16 + l16) * 64;
            bf16x8 b0 = *(const bf16x8*)(Vc + row + ((quad * 8) ^ swz));
            bf16x8 b1 = *(const bf16x8*)(Vc + row + ((32 + quad * 8) ^ swz));
            f32x4 a = {};
            a = __builtin_amdgcn_mfma_f32_16x16x32_bf16(b0, qv[0], a, 0, 0, 0);
            a = __builtin_amdgcn_mfma_f32_16x16x32_bf16(b1, qv[1], a, 0, 0, 0);
            s[t] = a;
        }
        __builtin_amdgcn_s_setprio(0);
        if (tail) {
#pragma unroll
            for (int t = 0; t < 4; t++)
#pragma unroll
                for (int r = 0; r < 4; r++)
                    if (key0 + t * 16 + kq4 + r >= N_) s[t][r] = -1e30f;
        }
#pragma unroll
        for (int t = 0; t < 4; t++) {
            const float p0 = fexp2(s[t][0]);
            const float p1 = fexp2(s[t][1]);
            const float p2 = fexp2(s[t][2]);
            const float p3 = fexp2(s[t][3]);
            *(uint2*)(&Ps[prow + (((t * 4 + quad) >> 1) ^ a7) * 8 + (quad & 1) * 4]) =
                make_uint2(pk2(p0, p1), pk2(p2, p3));
        }
        {
            bf16x8 pa0 = *(const bf16x8*)(&Ps[prow + ((quad    ) ^ a7) * 8]);
            bf16x8 pa1 = *(const bf16x8*)(&Ps[prow + ((quad + 4) ^ a7) * 8]);
            __builtin_amdgcn_s_setprio(1);
            lac1 = __builtin_amdgcn_mfma_f32_16x16x32_bf16(pa0, ones, lac1, 0, 0, 0);
            lac1 = __builtin_amdgcn_mfma_f32_16x16x32_bf16(pa1, ones, lac1, 0, 0, 0);
#pragma unroll
            for (int t = 0; t < 4; t++) {
                const int row = (t * 16 + l16) * 64;
                bf16x8 bv0 = *(const bf16x8*)(Tc + row + ((quad * 8) ^ swz));
                bf16x8 bv1 = *(const bf16x8*)(Tc + row + ((32 + quad * 8) ^ swz));
                o1[t] = __builtin_amdgcn_mfma_f32_16x16x32_bf16(pa0, bv0, o1[t], 0, 0, 0);
                o1[t] = __builtin_amdgcn_mfma_f32_16x16x32_bf16(pa1, bv1, o1[t], 0, 0, 0);
            }
            __builtin_amdgcn_s_setprio(0);
        }
    }

    // ---- epilogue: lac[r] = L[qrow = quad*4 + r] (all lanes) ----
#pragma unroll
    for (int r = 0; r < 4; r++) {
        const float inv0 = 1.0f / lac0[r];
        const float inv1 = 1.0f / lac1[r];
        const int row = qr0 + kq4 + r;
        const size_t rb = (size_t)(b * N_ + row) * C_ + h * HD;
#pragma unroll
        for (int t = 0; t < 4; t++) {
            const int d = t * 16 + l16;
            xori[rb + d] = f2bf(o0[t][r] * inv0);
            xvv[rb + d]  = f2bf(o1[t][r] * inv1);
        }
    }
}

// ---------------------------------------------------------------------------
// GEMM 2: OUT(f32) = Xcat(bf16) * Wbf^T + bias. Two-barrier K-loop +
// XCD-aware 1-D grid (r10).
// ---------------------------------------------------------------------------
__global__ __launch_bounds__(256)
void gemm_proj(const ushort_t* __restrict__ A, const ushort_t* __restrict__ Bm,
               const float* __restrict__ bias, float* __restrict__ out) {
    const int lin = blockIdx.x;
    const int xcd = lin & 7;
    const int j = lin >> 3;             // 0..135
    const int m_local = j % 17;         // m fastest within XCD
    const int n_idx = j / 17;           // 0..7
    const int m_idx = xcd * 17 + m_local;  // 0..135
    if (m_idx >= 129) return;
    const int m0 = m_idx * 128, n0 = n_idx * 128;

    __shared__ ushort_t As[128 * 32];
    __shared__ ushort_t Bs[128 * 32];
    const int tid = threadIdx.x;
    const int wave = tid >> 6, lane = tid & 63;
    const int quad = lane >> 4, l16 = lane & 15;
    const int wm = (wave & 1) * 64, wn = (wave >> 1) * 64;

    const int col8 = (tid & 3) * 8;
    const int row0 = tid >> 2;
    const int ar0 = min(m0 + row0,      M_PROJ - 1);
    const int ar1 = min(m0 + row0 + 64, M_PROJ - 1);
    const ushort_t* ga0 = A + (size_t)ar0 * K_ + col8;
    const ushort_t* ga1 = A + (size_t)ar1 * K_ + col8;
    const ushort_t* gb0 = Bm + (size_t)(n0 + row0) * K_ + col8;
    const ushort_t* gb1 = Bm + (size_t)(n0 + row0 + 64) * K_ + col8;
    ushort_t* lA0 = As + tid * 8;
    ushort_t* lA1 = As + (tid + 256) * 8;
    ushort_t* lB0 = Bs + tid * 8;
    ushort_t* lB1 = Bs + (tid + 256) * 8;

    f32x4 acc[4][4] = {};

    for (int k0 = 0; k0 < K_; k0 += 32) {
        __syncthreads();
        gload16(ga0 + k0, lA0);
        gload16(ga1 + k0, lA1);
        gload16(gb0 + k0, lB0);
        gload16(gb1 + k0, lB1);
        __syncthreads();
        bf16x8 af[4], bfr[4];
#pragma unroll
        for (int i = 0; i < 4; i++) {
            af[i]  = *(const bf16x8*)(As + (wm + i * 16 + l16) * 32 + quad * 8);
            bfr[i] = *(const bf16x8*)(Bs + (wn + i * 16 + l16) * 32 + quad * 8);
        }
#pragma unroll
        for (int im = 0; im < 4; im++)
#pragma unroll
            for (int in = 0; in < 4; in++)
                acc[im][in] = __builtin_amdgcn_mfma_f32_16x16x32_bf16(af[im], bfr[in], acc[im][in], 0, 0, 0);
    }

#pragma unroll
    for (int im = 0; im < 4; im++) {
#pragma unroll
        for (int in = 0; in < 4; in++) {
            const int gcol = n0 + wn + in * 16 + l16;
            const float bb = bias[gcol];
#pragma unroll
            for (int r = 0; r < 4; r++) {
                const int grow = m0 + wm + im * 16 + quad * 4 + r;
                if (grow < M_PROJ)
                    out[(size_t)grow * C_ + gcol] = acc[im][in][r] + bb;
            }
        }
    }
}

// ---------------------------------------------------------------------------
// Memory map:
//   d_ws  [0,S1)      : x_bf (phase 1), then xvv   [aliased]
//   d_ws  [S1,2S1)    : xori
//   d_ws  [2S1,3S1)   : v (phases 1-3), then wproj_bf [aliased, conv after attn]
//   d_out [0,S1)      : q (pre-scaled 0.125*log2e)   [dead before proj writes]
//   d_out [S1,2S1)    : k
//   d_out [2S1,2S1+VT): vT
//   d_out [2S1+VT,..) : wqkv_bf
// ---------------------------------------------------------------------------
extern "C" void kernel_launch(void* const* d_in, const int* in_sizes, int n_in,
                              void* d_out, int out_size, void* d_ws, size_t ws_size,
                              hipStream_t stream) {
    const float* x      = (const float*)d_in[0];
    const float* w_qkv  = (const float*)d_in[1];
    const float* w_proj = (const float*)d_in[2];
    const float* b_proj = (const float*)d_in[3];
    float* out = (float*)d_out;

    ushort_t* ws = (ushort_t*)d_ws;
    ushort_t* x_bf     = ws;
    ushort_t* xvv      = ws;
    ushort_t* xori     = ws + S1;
    ushort_t* v        = ws + 2 * S1;
    ushort_t* wproj_bf = ws + 2 * S1;

    ushort_t* q        = (ushort_t*)d_out;
    ushort_t* k        = (ushort_t*)d_out + S1;
    ushort_t* vT       = (ushort_t*)d_out + 2 * S1;
    ushort_t* wqkv_bf  = (ushort_t*)d_out + 2 * S1 + VT_SZ;

    {
        const int n8x = (int)(S1 / 8);
        const int n8w = 3 * C_ * C_ / 8;
        conv_bf16_2<<<(n8x + n8w + 255) / 256, 256, 0, stream>>>(
            x, x_bf, n8x, w_qkv, wqkv_bf, n8w);
    }
    {
        gemm_qkv<<<dim3(8 * 24 * 9), 256, 0, stream>>>(x_bf, wqkv_bf, q, k, v, vT);
    }
    {
        attn_kernel<<<dim3(9 * B_ * H_), 512, 0, stream>>>(q, k, v, vT, xvv, xori);
    }
    {
        const int n8p = C_ * C_ / 8;
        conv_bf16<<<(n8p + 255) / 256, 256, 0, stream>>>(w_proj, wproj_bf, n8p);
    }
    {
        gemm_proj<<<dim3(8 * 8 * 17), 256, 0, stream>>>(xvv, wproj_bf, b_proj, out);
    }
}